// Round 10
// baseline (90.597 us; speedup 1.0000x reference)
//
#include <hip/hip_runtime.h>
#include <hip/hip_bf16.h>

#define D_S 128

typedef short bf16x8 __attribute__((ext_vector_type(8)));
typedef float f32x4 __attribute__((ext_vector_type(4)));

__device__ __forceinline__ unsigned short f32_to_bf16(float f) {
  unsigned int u = __float_as_uint(f);
  return (unsigned short)((u + 0x7FFFu + ((u >> 16) & 1u)) >> 16);  // RN-even
}
__device__ __forceinline__ unsigned int pack2_bf16(float lo, float hi) {
  return (unsigned int)f32_to_bf16(lo) | ((unsigned int)f32_to_bf16(hi) << 16);
}
__device__ __forceinline__ bf16x8 cvt_frag(float4 x, float4 y) {
  union { bf16x8 v; unsigned int u[4]; } r;
  r.u[0] = pack2_bf16(x.x, x.y);
  r.u[1] = pack2_bf16(x.z, x.w);
  r.u[2] = pack2_bf16(y.x, y.y);
  r.u[3] = pack2_bf16(y.z, y.w);
  return r.v;
}

// ---------------------------------------------------------------------------
// Kernel 1 (MFMA, LDS-staged): AB[n][j] = Wc[j].s[n] (+b1[j] for j<128),
// bf16, interleaved layout. R9 -> R10: node tile 64 -> 32 (grid 782 -> 1564,
// ~3 -> ~6 blocks/CU) to halve the per-block serial chain that left R9's
// precompute latency-bound at ~25us (floor ~12). Same total traffic: s read
// once, AB written once. Per wave: afrag[2][4], 16 MFMA/chunk, 32 ds_write_b16
// D-pack total (was 128). Edge kernel byte-identical to R9's proven 52.6us.
// D layout (m89-verified): col=lane&15, row=(lane>>4)*4+reg.
// ---------------------------------------------------------------------------
__global__ __launch_bounds__(256) void precompute_mfma(
    const float* __restrict__ s, const float* __restrict__ W1,
    const float* __restrict__ b1, unsigned short* __restrict__ AB,
    int n_nodes) {
  __shared__ __align__(16) unsigned short s_tile[32 * 128];  // 8 KB, swizzled
  __shared__ __align__(16) unsigned short o_tile[32 * 256];  // 16 KB, swizzled
  int t = threadIdx.x;
  int wv = t >> 6, lane = t & 63;
  int lr = lane & 15, lc = lane >> 4;
  int n0 = blockIdx.x * 32;

  // ---- stage s: 32 rows x 128 f32 -> bf16 LDS (coalesced 32B/thread) ----
#pragma unroll
  for (int rep = 0; rep < 2; ++rep) {
    int idx = t + rep * 256;  // 512 chunks of 8 floats (32 rows x 16 groups)
    int row = idx >> 4;
    int c8 = (idx & 15) * 8;
    int gn = n0 + row;
    if (gn > n_nodes - 1) gn = n_nodes - 1;  // clamp; masked at store
    const float* sp = s + (size_t)gn * D_S + c8;
    float4 x = *(const float4*)sp;
    float4 y = *(const float4*)(sp + 4);
    bf16x8 pk = cvt_frag(x, y);
    int byte = (row * 256 + c8 * 2) ^ ((row & 7) << 4);
    *(bf16x8*)((char*)s_tile + byte) = pk;
  }
  __syncthreads();

  // ---- A fragments from LDS: 2 m-tiles x 4 k-steps ----
  bf16x8 afrag[2][4];
#pragma unroll
  for (int m = 0; m < 2; ++m) {
    int row = m * 16 + lr;
    int swz = (row & 7) << 4;
#pragma unroll
    for (int ks = 0; ks < 4; ++ks) {
      int byte = (row * 256 + lc * 16 + ks * 64) ^ swz;
      afrag[m][ks] = *(const bf16x8*)((const char*)s_tile + byte);
    }
  }

#pragma unroll 1
  for (int chunk = 0; chunk < 2; ++chunk) {
    // B fragments: Wc row j = chunk*128 + wv*32 + nt*16 + lr
    //   -> W1[j - chunk*128][chunk*128 + k]  (fp32, L2-hot, in-reg cvt)
    bf16x8 bfr[2][4];
#pragma unroll
    for (int nt = 0; nt < 2; ++nt) {
      const float* wrow =
          W1 + (size_t)(wv * 32 + nt * 16 + lr) * (2 * D_S) + chunk * D_S + lc * 8;
#pragma unroll
      for (int ks = 0; ks < 4; ++ks) {
        float4 x = *(const float4*)(wrow + ks * 32);
        float4 y = *(const float4*)(wrow + ks * 32 + 4);
        bfr[nt][ks] = cvt_frag(x, y);
      }
    }

    f32x4 acc[2][2] = {};
#pragma unroll
    for (int ks = 0; ks < 4; ++ks)
#pragma unroll
      for (int m = 0; m < 2; ++m)
#pragma unroll
        for (int nt = 0; nt < 2; ++nt)
          acc[m][nt] = __builtin_amdgcn_mfma_f32_16x16x32_bf16(
              afrag[m][ks], bfr[nt][ks], acc[m][nt], 0, 0, 0);

    if (chunk == 0) {  // bias on the A half only
#pragma unroll
      for (int nt = 0; nt < 2; ++nt) {
        float bv = b1[wv * 32 + nt * 16 + lr];
#pragma unroll
        for (int m = 0; m < 2; ++m)
#pragma unroll
          for (int r = 0; r < 4; ++r) acc[m][nt][r] += bv;
      }
    }

    // pack D -> o_tile (swizzled 2B stores; R7 measured 0 bank conflicts)
#pragma unroll
    for (int m = 0; m < 2; ++m)
#pragma unroll
      for (int nt = 0; nt < 2; ++nt) {
        int col = chunk * 128 + wv * 32 + nt * 16 + lr;
#pragma unroll
        for (int r = 0; r < 4; ++r) {
          int row = m * 16 + lc * 4 + r;
          int byte = (row * 512 + col * 2) ^ ((row & 7) << 4);
          *(unsigned short*)((char*)o_tile + byte) = f32_to_bf16(acc[m][nt][r]);
        }
      }
  }
  __syncthreads();

  // ---- interleaved copy-out: 32 nodes x 16 j-groups, 32B contiguous ----
#pragma unroll
  for (int rep = 0; rep < 2; ++rep) {
    int idx = t + rep * 256;  // 512 = 32 nodes x 16 j-groups
    int node = idx >> 4, jg = idx & 15;
    int gn = n0 + node;
    if (gn < n_nodes) {
      int sw = (node & 7) << 4;
      int base = node * 512 + jg * 32;
      uint4 v0 = *(const uint4*)((const char*)o_tile + (base ^ sw));
      uint4 v1 = *(const uint4*)((const char*)o_tile + ((base + 16) ^ sw));
      unsigned short* dst = AB + (size_t)gn * 256 + jg * 16;
      *(uint4*)dst = v0;
      *(uint4*)(dst + 8) = v1;
    }
  }
}

// ---------------------------------------------------------------------------
// Kernel 2: per-edge gather — UNCHANGED from R9 (proven 52.6us = the
// ~3.4TB/s L2-miss-path ceiling for this random pattern, reproduced across
// R5/R6/R9 at different VALU mixes; R7/R8 slicing alternatives were slower).
// 8 edges/wave, 8 lanes/edge, 16 k/lane:
//   out[e] = sum_k W2[k] * silu(A[row][k] + B[col][k]) + b2
// ---------------------------------------------------------------------------
__device__ __forceinline__ float silu2(unsigned int ua, unsigned int ub,
                                       float wlo, float whi) {
  float h0 = __uint_as_float(ua << 16) + __uint_as_float(ub << 16);
  float h1 = __uint_as_float(ua & 0xFFFF0000u) + __uint_as_float(ub & 0xFFFF0000u);
  float e0 = __builtin_amdgcn_exp2f(h0 * -1.442695041f);
  float e1 = __builtin_amdgcn_exp2f(h1 * -1.442695041f);
  float r0 = __builtin_amdgcn_rcpf(1.f + e0);
  float r1 = __builtin_amdgcn_rcpf(1.f + e1);
  return h0 * r0 * wlo + h1 * r1 * whi;
}

__global__ __launch_bounds__(256) void edge_kernel(
    const int* __restrict__ ei, const unsigned short* __restrict__ AB,
    const float* __restrict__ W2, const float* __restrict__ b2,
    float* __restrict__ out, int E) {
  int t = threadIdx.x;
  int wv = (blockIdx.x << 2) + (t >> 6);
  int lane = t & 63;
  int g = lane >> 3, sub = lane & 7;
  int e = wv * 8 + g;
  if (e >= E) e = E - 1;  // duplicate tail edge: deterministic, same value

  int row = ei[e];
  int col = ei[E + e];

  unsigned int sh = (unsigned int)(sub << 4);
  unsigned int offA = ((unsigned int)row << 8) + sh;
  unsigned int offB = ((unsigned int)col << 8) + 128 + sh;
  uint4 a0 = *(const uint4*)(AB + offA);
  uint4 a1 = *(const uint4*)(AB + offA + 8);
  uint4 b0 = *(const uint4*)(AB + offB);
  uint4 b1v = *(const uint4*)(AB + offB + 8);

  const float4* wp = (const float4*)(W2 + (sub << 4));
  float4 w0 = wp[0], w1 = wp[1], w2 = wp[2], w3 = wp[3];

  float p = 0.f;
  p += silu2(a0.x, b0.x, w0.x, w0.y);
  p += silu2(a0.y, b0.y, w0.z, w0.w);
  p += silu2(a0.z, b0.z, w1.x, w1.y);
  p += silu2(a0.w, b0.w, w1.z, w1.w);
  p += silu2(a1.x, b1v.x, w2.x, w2.y);
  p += silu2(a1.y, b1v.y, w2.z, w2.w);
  p += silu2(a1.z, b1v.z, w3.x, w3.y);
  p += silu2(a1.w, b1v.w, w3.z, w3.w);

#pragma unroll
  for (int off = 1; off < 8; off <<= 1) p += __shfl_xor(p, off, 64);

  if (sub == 0) out[e] = p + b2[0];
}

// ---------------------------------------------------------------------------
// Fallback (workspace too small): direct per-edge compute, fp32.
// ---------------------------------------------------------------------------
__global__ __launch_bounds__(256) void edge_direct(
    const float* __restrict__ s, const int* __restrict__ ei,
    const float* __restrict__ W1, const float* __restrict__ b1,
    const float* __restrict__ W2, const float* __restrict__ b2,
    float* __restrict__ out, int E) {
  __shared__ float sh[256];
  __shared__ float red[128];
  int e = blockIdx.x;
  int t = threadIdx.x;
  int row = ei[e], col = ei[E + e];
  sh[t] = (t < 128) ? s[(size_t)row * D_S + t] : s[(size_t)col * D_S + (t - 128)];
  __syncthreads();
  if (t < 128) {
    float acc = b1[t];
    const float* w = W1 + (size_t)t * 256;
#pragma unroll 8
    for (int jj = 0; jj < 256; ++jj) acc += sh[jj] * w[jj];
    red[t] = (acc / (1.f + __expf(-acc))) * W2[t];
  }
  __syncthreads();
  if (t < 64) {
    float x = red[t] + red[t + 64];
#pragma unroll
    for (int off = 32; off; off >>= 1) x += __shfl_xor(x, off, 64);
    if (t == 0) out[e] = x + b2[0];
  }
}

extern "C" void kernel_launch(void* const* d_in, const int* in_sizes, int n_in,
                              void* d_out, int out_size, void* d_ws, size_t ws_size,
                              hipStream_t stream) {
  const float* s  = (const float*)d_in[0];
  const int*   ei = (const int*)d_in[1];
  const float* W1 = (const float*)d_in[2];
  const float* b1 = (const float*)d_in[3];
  const float* W2 = (const float*)d_in[4];
  const float* b2 = (const float*)d_in[5];
  float* out = (float*)d_out;

  int n_nodes = in_sizes[0] / D_S;
  int E = in_sizes[1] / 2;

  size_t need = (size_t)n_nodes * 256 * sizeof(unsigned short);
  if (ws_size >= need) {
    unsigned short* AB = (unsigned short*)d_ws;
    precompute_mfma<<<(n_nodes + 31) / 32, 256, 0, stream>>>(s, W1, b1, AB,
                                                             n_nodes);
    int blocks = (E + 31) / 32;  // 4 waves/block, 8 edges/wave
    edge_kernel<<<blocks, 256, 0, stream>>>(ei, AB, W2, b2, out, E);
  } else {
    edge_direct<<<E, 256, 0, stream>>>(s, ei, W1, b1, W2, b2, out, E);
  }
}

// Round 11
// 78.144 us; speedup vs baseline: 1.1594x; 1.1594x over previous
//
#include <hip/hip_runtime.h>
#include <hip/hip_bf16.h>

#define D_S 128

typedef short bf16x8 __attribute__((ext_vector_type(8)));
typedef float f32x4 __attribute__((ext_vector_type(4)));

__device__ __forceinline__ unsigned short f32_to_bf16(float f) {
  unsigned int u = __float_as_uint(f);
  return (unsigned short)((u + 0x7FFFu + ((u >> 16) & 1u)) >> 16);  // RN-even
}
__device__ __forceinline__ unsigned int pack2_bf16(float lo, float hi) {
  return (unsigned int)f32_to_bf16(lo) | ((unsigned int)f32_to_bf16(hi) << 16);
}
__device__ __forceinline__ bf16x8 cvt_frag(float4 x, float4 y) {
  union { bf16x8 v; unsigned int u[4]; } r;
  r.u[0] = pack2_bf16(x.x, x.y);
  r.u[1] = pack2_bf16(x.z, x.w);
  r.u[2] = pack2_bf16(y.x, y.y);
  r.u[3] = pack2_bf16(y.z, y.w);
  return r.v;
}

// ---------------------------------------------------------------------------
// Kernel 1 (MFMA, LDS-staged): AB[n][j] = Wc[j].s[n] (+b1[j] for j<128),
// bf16, interleaved layout. Grid (ceil(n/64), 2): 64-node x 128-j tile,
// chunk = blockIdx.y.
// R10 post-mortem: halving the NODE tile doubled per-block W1 read+cvt
// (200MB total) -> regression. This splits the CHUNK axis instead: per-block
// W1 read halves (64KB), total W1 traffic unchanged vs R9 (100MB), s read 2x
// (L3-resident, cheap), serial chain halved, LDS 48->32KB, blocks 782->1564.
// D layout (m89-verified): col=lane&15, row=(lane>>4)*4+reg.
// ---------------------------------------------------------------------------
__global__ __launch_bounds__(256) void precompute_mfma(
    const float* __restrict__ s, const float* __restrict__ W1,
    const float* __restrict__ b1, unsigned short* __restrict__ AB,
    int n_nodes) {
  __shared__ __align__(16) unsigned short s_tile[64 * 128];  // 16 KB, swizzled
  __shared__ __align__(16) unsigned short o_tile[64 * 128];  // 16 KB, swizzled
  int t = threadIdx.x;
  int wv = t >> 6, lane = t & 63;
  int lr = lane & 15, lc = lane >> 4;
  int n0 = blockIdx.x * 64;
  int chunk = blockIdx.y;

  // ---- stage s: 64 rows x 128 f32 -> bf16 LDS (coalesced 32B/thread) ----
#pragma unroll
  for (int rep = 0; rep < 4; ++rep) {
    int idx = t + rep * 256;  // 1024 chunks of 8 floats
    int row = idx >> 4;
    int c8 = (idx & 15) * 8;
    int gn = n0 + row;
    if (gn > n_nodes - 1) gn = n_nodes - 1;  // clamp; masked at store
    const float* sp = s + (size_t)gn * D_S + c8;
    float4 x = *(const float4*)sp;
    float4 y = *(const float4*)(sp + 4);
    bf16x8 pk = cvt_frag(x, y);
    int byte = (row * 256 + c8 * 2) ^ ((row & 7) << 4);
    *(bf16x8*)((char*)s_tile + byte) = pk;
  }

  // ---- B fragments (independent of s_tile: issue before the barrier) ----
  // Wc row j = chunk*128 + wv*32 + nt*16 + lr -> W1[j-chunk*128][chunk*128+k]
  bf16x8 bfr[2][4];
#pragma unroll
  for (int nt = 0; nt < 2; ++nt) {
    const float* wrow =
        W1 + (size_t)(wv * 32 + nt * 16 + lr) * (2 * D_S) + chunk * D_S + lc * 8;
#pragma unroll
    for (int ks = 0; ks < 4; ++ks) {
      float4 x = *(const float4*)(wrow + ks * 32);
      float4 y = *(const float4*)(wrow + ks * 32 + 4);
      bfr[nt][ks] = cvt_frag(x, y);
    }
  }
  __syncthreads();

  // ---- A fragments from LDS ----
  bf16x8 afrag[4][4];
#pragma unroll
  for (int m = 0; m < 4; ++m) {
    int row = m * 16 + lr;
    int swz = (row & 7) << 4;
#pragma unroll
    for (int ks = 0; ks < 4; ++ks) {
      int byte = (row * 256 + lc * 16 + ks * 64) ^ swz;
      afrag[m][ks] = *(const bf16x8*)((const char*)s_tile + byte);
    }
  }

  f32x4 acc[4][2] = {};
#pragma unroll
  for (int ks = 0; ks < 4; ++ks)
#pragma unroll
    for (int m = 0; m < 4; ++m)
#pragma unroll
      for (int nt = 0; nt < 2; ++nt)
        acc[m][nt] = __builtin_amdgcn_mfma_f32_16x16x32_bf16(
            afrag[m][ks], bfr[nt][ks], acc[m][nt], 0, 0, 0);

  if (chunk == 0) {  // bias on the A half only
#pragma unroll
    for (int nt = 0; nt < 2; ++nt) {
      float bv = b1[wv * 32 + nt * 16 + lr];
#pragma unroll
      for (int m = 0; m < 4; ++m)
#pragma unroll
        for (int r = 0; r < 4; ++r) acc[m][nt][r] += bv;
    }
  }

  // pack D -> o_tile (swizzled 2B stores; measured 0 bank conflicts in R7)
#pragma unroll
  for (int m = 0; m < 4; ++m)
#pragma unroll
    for (int nt = 0; nt < 2; ++nt) {
      int col = wv * 32 + nt * 16 + lr;  // within this chunk's 128 j
#pragma unroll
      for (int r = 0; r < 4; ++r) {
        int row = m * 16 + lc * 4 + r;
        int byte = (row * 256 + col * 2) ^ ((row & 7) << 4);
        *(unsigned short*)((char*)o_tile + byte) = f32_to_bf16(acc[m][nt][r]);
      }
    }
  __syncthreads();

  // ---- copy-out: 64 nodes x 8 j-groups of 16, 32B contiguous/thread ----
#pragma unroll
  for (int rep = 0; rep < 2; ++rep) {
    int idx = t + rep * 256;  // 512 = 64 nodes x 8 j-groups
    int node = idx >> 3, jg = idx & 7;
    int gn = n0 + node;
    if (gn < n_nodes) {
      int sw = (node & 7) << 4;
      int base = node * 256 + jg * 32;
      uint4 v0 = *(const uint4*)((const char*)o_tile + (base ^ sw));
      uint4 v1 = *(const uint4*)((const char*)o_tile + ((base + 16) ^ sw));
      unsigned short* dst = AB + (size_t)gn * 256 + chunk * 128 + jg * 16;
      *(uint4*)dst = v0;
      *(uint4*)(dst + 8) = v1;
    }
  }
}

// ---------------------------------------------------------------------------
// Kernel 2: per-edge gather — UNCHANGED from R9 (proven 52.3-52.8us across
// 4 rounds = the ~3.4TB/s L2-capacity-miss ceiling for this random pattern;
// gathers are fully-coalesced 256B chunks, every fetched line fully used;
// R7/R8 L2-resident slicing alternatives were slower).
// 8 edges/wave, 8 lanes/edge, 16 k/lane:
//   out[e] = sum_k W2[k] * silu(A[row][k] + B[col][k]) + b2
// ---------------------------------------------------------------------------
__device__ __forceinline__ float silu2(unsigned int ua, unsigned int ub,
                                       float wlo, float whi) {
  float h0 = __uint_as_float(ua << 16) + __uint_as_float(ub << 16);
  float h1 = __uint_as_float(ua & 0xFFFF0000u) + __uint_as_float(ub & 0xFFFF0000u);
  float e0 = __builtin_amdgcn_exp2f(h0 * -1.442695041f);
  float e1 = __builtin_amdgcn_exp2f(h1 * -1.442695041f);
  float r0 = __builtin_amdgcn_rcpf(1.f + e0);
  float r1 = __builtin_amdgcn_rcpf(1.f + e1);
  return h0 * r0 * wlo + h1 * r1 * whi;
}

__global__ __launch_bounds__(256) void edge_kernel(
    const int* __restrict__ ei, const unsigned short* __restrict__ AB,
    const float* __restrict__ W2, const float* __restrict__ b2,
    float* __restrict__ out, int E) {
  int t = threadIdx.x;
  int wv = (blockIdx.x << 2) + (t >> 6);
  int lane = t & 63;
  int g = lane >> 3, sub = lane & 7;
  int e = wv * 8 + g;
  if (e >= E) e = E - 1;  // duplicate tail edge: deterministic, same value

  int row = ei[e];
  int col = ei[E + e];

  unsigned int sh = (unsigned int)(sub << 4);
  unsigned int offA = ((unsigned int)row << 8) + sh;
  unsigned int offB = ((unsigned int)col << 8) + 128 + sh;
  uint4 a0 = *(const uint4*)(AB + offA);
  uint4 a1 = *(const uint4*)(AB + offA + 8);
  uint4 b0 = *(const uint4*)(AB + offB);
  uint4 b1v = *(const uint4*)(AB + offB + 8);

  const float4* wp = (const float4*)(W2 + (sub << 4));
  float4 w0 = wp[0], w1 = wp[1], w2 = wp[2], w3 = wp[3];

  float p = 0.f;
  p += silu2(a0.x, b0.x, w0.x, w0.y);
  p += silu2(a0.y, b0.y, w0.z, w0.w);
  p += silu2(a0.z, b0.z, w1.x, w1.y);
  p += silu2(a0.w, b0.w, w1.z, w1.w);
  p += silu2(a1.x, b1v.x, w2.x, w2.y);
  p += silu2(a1.y, b1v.y, w2.z, w2.w);
  p += silu2(a1.z, b1v.z, w3.x, w3.y);
  p += silu2(a1.w, b1v.w, w3.z, w3.w);

#pragma unroll
  for (int off = 1; off < 8; off <<= 1) p += __shfl_xor(p, off, 64);

  if (sub == 0) out[e] = p + b2[0];
}

// ---------------------------------------------------------------------------
// Fallback (workspace too small): direct per-edge compute, fp32.
// ---------------------------------------------------------------------------
__global__ __launch_bounds__(256) void edge_direct(
    const float* __restrict__ s, const int* __restrict__ ei,
    const float* __restrict__ W1, const float* __restrict__ b1,
    const float* __restrict__ W2, const float* __restrict__ b2,
    float* __restrict__ out, int E) {
  __shared__ float sh[256];
  __shared__ float red[128];
  int e = blockIdx.x;
  int t = threadIdx.x;
  int row = ei[e], col = ei[E + e];
  sh[t] = (t < 128) ? s[(size_t)row * D_S + t] : s[(size_t)col * D_S + (t - 128)];
  __syncthreads();
  if (t < 128) {
    float acc = b1[t];
    const float* w = W1 + (size_t)t * 256;
#pragma unroll 8
    for (int jj = 0; jj < 256; ++jj) acc += sh[jj] * w[jj];
    red[t] = (acc / (1.f + __expf(-acc))) * W2[t];
  }
  __syncthreads();
  if (t < 64) {
    float x = red[t] + red[t + 64];
#pragma unroll
    for (int off = 32; off; off >>= 1) x += __shfl_xor(x, off, 64);
    if (t == 0) out[e] = x + b2[0];
  }
}

extern "C" void kernel_launch(void* const* d_in, const int* in_sizes, int n_in,
                              void* d_out, int out_size, void* d_ws, size_t ws_size,
                              hipStream_t stream) {
  const float* s  = (const float*)d_in[0];
  const int*   ei = (const int*)d_in[1];
  const float* W1 = (const float*)d_in[2];
  const float* b1 = (const float*)d_in[3];
  const float* W2 = (const float*)d_in[4];
  const float* b2 = (const float*)d_in[5];
  float* out = (float*)d_out;

  int n_nodes = in_sizes[0] / D_S;
  int E = in_sizes[1] / 2;

  size_t need = (size_t)n_nodes * 256 * sizeof(unsigned short);
  if (ws_size >= need) {
    unsigned short* AB = (unsigned short*)d_ws;
    dim3 g1((n_nodes + 63) / 64, 2);
    precompute_mfma<<<g1, 256, 0, stream>>>(s, W1, b1, AB, n_nodes);
    int blocks = (E + 31) / 32;  // 4 waves/block, 8 edges/wave
    edge_kernel<<<blocks, 256, 0, stream>>>(ei, AB, W2, b2, out, E);
  } else {
    edge_direct<<<E, 256, 0, stream>>>(s, ei, W1, b1, W2, b2, out, E);
  }
}